// Round 1
// baseline (532.119 us; speedup 1.0000x reference)
//
#include <hip/hip_runtime.h>
#include <cstdint>
#include <cstddef>

#define NEGV (-1e30f)
#define IL2f 1.44269504088896340736f
#define LN2f 0.693147180559945309417f

#if __has_builtin(__builtin_amdgcn_exp2f)
__device__ __forceinline__ float exp2_hw(float x) { return __builtin_amdgcn_exp2f(x); }
#else
__device__ __forceinline__ float exp2_hw(float x) { return exp2f(x); }
#endif
#if __has_builtin(__builtin_amdgcn_logf)
__device__ __forceinline__ float log2_hw(float x) { return __builtin_amdgcn_logf(x); }
#else
__device__ __forceinline__ float log2_hw(float x) { return log2f(x); }
#endif

constexpr int Nn = 64, Cc = 64, Tt = 4000, Ss = 100;

// ---------------- Kernel 1: per-(n,t) log2-sum-exp2 denominator ----------------
__global__ __launch_bounds__(256) void ctc_denom_kernel(
    const float* __restrict__ logits, float* __restrict__ d2)
{
    const int t = blockIdx.x * 256 + threadIdx.x;
    const int n = blockIdx.y;
    if (t >= Tt) return;
    const float* __restrict__ p = logits + (size_t)n * Cc * Tt + t;
    float mx = p[0];
    #pragma unroll 8
    for (int c = 1; c < Cc; ++c) mx = fmaxf(mx, p[(size_t)c * Tt]);
    float sum = 0.f;
    #pragma unroll 8
    for (int c = 0; c < Cc; ++c) sum += exp2_hw((p[(size_t)c * Tt] - mx) * IL2f);
    d2[(size_t)n * Tt + t] = mx * IL2f + log2_hw(sum);
}

// ---------------- Kernel 2: forward/backward serial recurrence ----------------
// blockIdx.x = 2*n + dir; dir 0: alpha over t=0..mid, dir 1: beta over t=Tn-1..mid+1.
// 256 threads = 4 waves; thread tid owns extended-position s = tid (L = 2*tl+1 <= 201).
// Cross-wave boundary values exchanged through tiny ping-pong LDS, 1 barrier/step.
typedef float f4 __attribute__((ext_vector_type(4)));
#define LD4(p) (*(const f4*)(p))
#define E8(a0, a1, k) ((k) < 4 ? (a0)[(k)] : (a1)[(k) - 4])

__global__ __launch_bounds__(256) void ctc_fb_kernel(
    const float* __restrict__ logits, const int* __restrict__ targets,
    const int* __restrict__ tlen, const int* __restrict__ ilen,
    const float* __restrict__ d2, float* __restrict__ wsA, float* __restrict__ wsB)
{
    const int bid = blockIdx.x;
    const int n = bid >> 1;
    const bool bwd = bid & 1;
    const int tid = threadIdx.x;
    const int lane = tid & 63;
    const int w = tid >> 6;
    const int tl = tlen[n];
    const int Tn = ilen[n];
    const int L = 2 * tl + 1;
    const int mid = Tn >> 1;

    __shared__ float bnd[2][5][2];
    if (tid < 2) {
        bnd[0][0][tid] = NEGV; bnd[1][0][tid] = NEGV;   // fwd: wave0 reads slot 0
        bnd[0][3][tid] = NEGV; bnd[1][3][tid] = NEGV;   // bwd: wave3 reads slot 3
    }

    const int s = tid;
    const bool vld = s < L;
    int lab = 0;
    bool skip = false;
    if (s & 1) {
        const int j = s >> 1;
        if (vld) lab = targets[n * Ss + j];
        if (!bwd) skip = vld && (s >= 3) && (targets[n * Ss + j] != targets[n * Ss + j - 1]);
        else      skip = (s + 2 < L) && (targets[n * Ss + j + 1] != targets[n * Ss + j]);
    }
    const float* __restrict__ lrow = logits + ((size_t)(n * Cc + lab)) * Tt;
    const float* __restrict__ drow = d2 + (size_t)n * Tt;

    float a;
    if (!bwd) {
        const float lpt = fmaf(lrow[0], IL2f, -drow[0]);
        a = (vld && s < 2) ? lpt : NEGV;
        if (lane >= 62) bnd[0][w + 1][lane - 62] = a;      // publish init boundary
    } else {
        const int te = Tn - 1;
        const float lpt = fmaf(lrow[te], IL2f, -drow[te]);
        a = (s == 2 * tl || s == 2 * tl - 1) ? lpt : NEGV;
        if (w > 0 && lane < 2) bnd[0][w - 1][lane] = a;    // publish init boundary
    }
    __syncthreads();
    int pp = 0;

    if (!bwd) {
        const int tB = mid;                  // steps t = 1..mid
        const int gHi = tB >> 3;
        f4 c0 = LD4(lrow), c1 = LD4(lrow + 4), e0 = LD4(drow), e1 = LD4(drow + 4);
        f4 p0, p1, q0, q1;
        for (int g = 0; g <= gHi; ++g) {
            if (g < gHi) {
                const int b = (g + 1) * 8;
                p0 = LD4(lrow + b); p1 = LD4(lrow + b + 4);
                q0 = LD4(drow + b); q1 = LD4(drow + b + 4);
            }
            #pragma unroll
            for (int k = 0; k < 8; ++k) {
                const int t = g * 8 + k;
                if (t < 1 || t > tB) continue;             // block-uniform
                const float lpt = fmaf(E8(c0, c1, k), IL2f, -E8(e0, e1, k));
                float x1 = __shfl_up(a, 1);
                float x2 = __shfl_up(a, 2);
                const float2 bv = *(const float2*)&bnd[pp][w][0];
                if (lane == 0)      { x1 = bv.y; x2 = bv.x; }
                else if (lane == 1) { x2 = bv.y; }
                x2 = skip ? x2 : NEGV;
                const float m3 = fmaxf(fmaxf(a, x1), x2);
                const float sm = exp2_hw(a - m3) + exp2_hw(x1 - m3) + exp2_hw(x2 - m3);
                a = m3 + log2_hw(sm) + lpt;
                if (lane >= 62) bnd[pp ^ 1][w + 1][lane - 62] = a;
                __syncthreads();
                pp ^= 1;
            }
            if (g < gHi) { c0 = p0; c1 = p1; e0 = q0; e1 = q1; }
        }
    } else {
        const int tB = Tn - 2, tA = mid + 1; // steps t = Tn-2 .. mid+1 (descending)
        const int gHi = tB >> 3, gLo = tA >> 3;
        f4 c0 = LD4(lrow + gHi * 8), c1 = LD4(lrow + gHi * 8 + 4);
        f4 e0 = LD4(drow + gHi * 8), e1 = LD4(drow + gHi * 8 + 4);
        f4 p0, p1, q0, q1;
        for (int g = gHi; g >= gLo; --g) {
            if (g > gLo) {
                const int b = (g - 1) * 8;
                p0 = LD4(lrow + b); p1 = LD4(lrow + b + 4);
                q0 = LD4(drow + b); q1 = LD4(drow + b + 4);
            }
            #pragma unroll
            for (int k = 7; k >= 0; --k) {
                const int t = g * 8 + k;
                if (t > tB || t < tA) continue;            // block-uniform
                const float lpt = fmaf(E8(c0, c1, k), IL2f, -E8(e0, e1, k));
                float x1 = __shfl_down(a, 1);
                float x2 = __shfl_down(a, 2);
                const float2 bv = *(const float2*)&bnd[pp][w][0];
                if (lane == 63)      { x1 = bv.x; x2 = bv.y; }
                else if (lane == 62) { x2 = bv.x; }
                x2 = skip ? x2 : NEGV;
                const float m3 = fmaxf(fmaxf(a, x1), x2);
                const float sm = exp2_hw(a - m3) + exp2_hw(x1 - m3) + exp2_hw(x2 - m3);
                a = m3 + log2_hw(sm) + lpt;
                if (w > 0 && lane < 2) bnd[pp ^ 1][w - 1][lane] = a;
                __syncthreads();
                pp ^= 1;
            }
            if (g > gLo) { c0 = p0; c1 = p1; e0 = q0; e1 = q1; }
        }
    }
    float* dst = (bwd ? wsB : wsA) + n * 256;
    dst[s] = vld ? a : NEGV;
}

// ---------------- Kernel 3: splice alpha*beta, lse over states, mean ----------------
__global__ __launch_bounds__(64) void ctc_combine_kernel(
    const float* __restrict__ wsA, const float* __restrict__ wsB,
    const int* __restrict__ targets, const int* __restrict__ tlen,
    float* __restrict__ out)
{
    const int n = blockIdx.x;
    const int lane = threadIdx.x;
    const int tl = tlen[n];
    const int L = 2 * tl + 1;
    float vals[4];
    float vmax = NEGV;
    #pragma unroll
    for (int k = 0; k < 4; ++k) {
        const int s = lane + (k << 6);
        float v = NEGV;
        if (s < L) {
            const float al = wsA[n * 256 + s];
            const float b0 = wsB[n * 256 + s];
            const float b1 = (s + 1 < L) ? wsB[n * 256 + s + 1] : NEGV;
            const bool skip = (s & 1) && (s + 2 < L) &&
                (targets[n * Ss + (s >> 1) + 1] != targets[n * Ss + (s >> 1)]);
            const float b2 = skip ? wsB[n * 256 + s + 2] : NEGV;
            const float m3 = fmaxf(fmaxf(b0, b1), b2);
            const float B = m3 + log2_hw(exp2_hw(b0 - m3) + exp2_hw(b1 - m3) + exp2_hw(b2 - m3));
            v = al + B;
        }
        vals[k] = v;
        vmax = fmaxf(vmax, v);
    }
    #pragma unroll
    for (int o = 32; o; o >>= 1) vmax = fmaxf(vmax, __shfl_xor(vmax, o));
    float ssum = 0.f;
    #pragma unroll
    for (int k = 0; k < 4; ++k) ssum += exp2_hw(vals[k] - vmax);
    #pragma unroll
    for (int o = 32; o; o >>= 1) ssum += __shfl_xor(ssum, o);
    if (lane == 0) {
        const float total2 = vmax + log2_hw(ssum);
        const float loss = -LN2f * total2;                  // back to natural log
        atomicAdd(out, loss / ((float)tl * (float)Nn));
    }
}

extern "C" void kernel_launch(void* const* d_in, const int* in_sizes, int n_in,
                              void* d_out, int out_size, void* d_ws, size_t ws_size,
                              hipStream_t stream) {
    const float* logits = (const float*)d_in[0];
    const int* targets  = (const int*)d_in[1];
    const int* tlen     = (const int*)d_in[2];
    const int* ilen     = (const int*)d_in[3];
    float* out = (float*)d_out;

    float* wsA = (float*)d_ws;            // 64*256 floats: alpha at t=mid
    float* wsB = wsA + Nn * 256;          // 64*256 floats: beta  at t=mid+1
    float* d2  = wsB + Nn * 256;          // 64*4000 floats: log2-softmax denominators

    hipMemsetAsync(d_out, 0, sizeof(float), stream);
    ctc_denom_kernel<<<dim3((Tt + 255) / 256, Nn), 256, 0, stream>>>(logits, d2);
    ctc_fb_kernel<<<Nn * 2, 256, 0, stream>>>(logits, targets, tlen, ilen, d2, wsA, wsB);
    ctc_combine_kernel<<<Nn, 64, 0, stream>>>(wsA, wsB, targets, tlen, out);
}

// Round 2
// 343.478 us; speedup vs baseline: 1.5492x; 1.5492x over previous
//
#include <hip/hip_runtime.h>
#include <cstdint>
#include <cstddef>

#define NEGV (-1e30f)
#define IL2f 1.44269504088896340736f
#define LN2f 0.693147180559945309417f

__device__ __forceinline__ float exp2_hw(float x) { return __builtin_amdgcn_exp2f(x); }
__device__ __forceinline__ float log2_hw(float x) { return __builtin_amdgcn_logf(x); }

constexpr int Nn = 64, Cc = 64, Tt = 4000, Ss = 100;

// DPP full-wave shifts (GFX9 wave_shr1/wave_shl1). row_shr:k => lane n reads lane n-k.
__device__ __forceinline__ float wave_shr1(float x) {  // lane n <- lane n-1 (shfl_up 1)
    return __int_as_float(__builtin_amdgcn_update_dpp(0, __float_as_int(x), 0x138, 0xF, 0xF, true));
}
__device__ __forceinline__ float wave_shl1(float x) {  // lane n <- lane n+1 (shfl_down 1)
    return __int_as_float(__builtin_amdgcn_update_dpp(0, __float_as_int(x), 0x130, 0xF, 0xF, true));
}

// log2-domain logsumexp; one exp2 saved via max/med/min sort.
__device__ __forceinline__ float lse2_2(float a, float b) {
    float m = fmaxf(a, b);
    float d = fminf(a, b) - m;
    return m + log2_hw(1.f + exp2_hw(d));
}
__device__ __forceinline__ float lse3_2(float a, float b, float c) {
    float m  = fmaxf(fmaxf(a, b), c);
    float md = __builtin_amdgcn_fmed3f(a, b, c);
    float lo = fminf(fminf(a, b), c);
    return m + log2_hw(1.f + exp2_hw(md - m) + exp2_hw(lo - m));
}

typedef float f4 __attribute__((ext_vector_type(4)));
#define LD4(p) (*(const f4*)(p))
#define E8(a0, a1, k) ((k) < 4 ? (a0)[(k)] : (a1)[(k) - 4])

// ---------------- Kernel 1: per-(n,t) log2-softmax denominator, single pass ----------------
__global__ __launch_bounds__(256) void ctc_denom_kernel(
    const float* __restrict__ logits, float* __restrict__ d2)
{
    const int t4 = (blockIdx.x * 256 + threadIdx.x) * 4;
    const int n = blockIdx.y;
    if (t4 >= Tt) return;
    const float* __restrict__ p = logits + (size_t)n * Cc * Tt + t4;
    f4 m, s;
    {
        f4 v = LD4(p);
        #pragma unroll
        for (int i = 0; i < 4; ++i) { m[i] = v[i] * IL2f; s[i] = 1.f; }
    }
    #pragma unroll 4
    for (int c = 1; c < Cc; ++c) {
        f4 v = LD4(p + (size_t)c * Tt);
        #pragma unroll
        for (int i = 0; i < 4; ++i) {
            float vi = v[i] * IL2f;
            float nm = fmaxf(m[i], vi);
            s[i] = s[i] * exp2_hw(m[i] - nm) + exp2_hw(vi - nm);
            m[i] = nm;
        }
    }
    f4 o;
    #pragma unroll
    for (int i = 0; i < 4; ++i) o[i] = m[i] + log2_hw(s[i]);
    *(f4*)(d2 + (size_t)n * Tt + t4) = o;
}

// ---------------- Kernel 2: forward/backward serial recurrence, single wave ----------------
// blockIdx.x = 2*n + dir. 64 threads = 1 wave; lane owns states s = 4*lane + k, k=0..3.
// Blocked layout => in-wave neighbors are register-local; only one/two DPP shifts per step.
// No LDS, no barriers.
__global__ __launch_bounds__(64) void ctc_fb_kernel(
    const float* __restrict__ logits, const int* __restrict__ targets,
    const int* __restrict__ tlen, const int* __restrict__ ilen,
    const float* __restrict__ d2, float* __restrict__ wsA, float* __restrict__ wsB)
{
    const int bid = blockIdx.x;
    const int n = bid >> 1;
    const bool bwd = bid & 1;
    const int lane = threadIdx.x;            // 0..63
    const int tl = tlen[n];
    const int Tn = ilen[n];
    const int L = 2 * tl + 1;
    const int mid = Tn >> 1;
    const int s0 = 4 * lane;

    // labels for odd slots (clamped indices for invalid lanes; values masked later)
    const int j1 = min(2 * lane, Ss - 1);        // slot1: s=4l+1 -> j=2l
    const int j3 = min(2 * lane + 1, Ss - 1);    // slot3: s=4l+3 -> j=2l+1
    const int base = n * Ss;
    const int tg1 = targets[base + j1];
    const int tg3 = targets[base + j3];
    const int tg1m = targets[base + max(2 * lane - 1, 0)];     // tgt[j1-1]
    const int tg3p = targets[base + min(2 * lane + 2, Ss - 1)];// tgt[j3+1]

    // skip-transition flags
    const bool skip1f = (s0 + 1 >= 3) && (tg1 != tg1m);        // fwd, slot1 (s-2)
    const bool skip3f = (tg3 != tg1);                          // fwd, slot3 (s>=3 always)
    const bool skip1b = (s0 + 3 < L) && (tg3 != tg1);          // bwd, slot1 (s+2)
    const bool skip3b = (s0 + 5 < L) && (tg3p != tg3);         // bwd, slot3 (s+2)

    const float* __restrict__ rB = logits + (size_t)(n * Cc) * Tt;        // blank row
    const float* __restrict__ r1 = logits + (size_t)(n * Cc + tg1) * Tt;  // slot1 row
    const float* __restrict__ r3 = logits + (size_t)(n * Cc + tg3) * Tt;  // slot3 row
    const float* __restrict__ rD = d2 + (size_t)n * Tt;

    float a0, a1, a2, a3;
    if (!bwd) {
        const float dv = rD[0];
        a0 = (lane == 0) ? fmaf(rB[0], IL2f, -dv) : NEGV;   // s=0
        a1 = (lane == 0) ? fmaf(r1[0], IL2f, -dv) : NEGV;   // s=1
        a2 = NEGV; a3 = NEGV;
    } else {
        const int te = Tn - 1;
        const float dv = rD[te];
        const float lB = fmaf(rB[te], IL2f, -dv);
        const float l1 = fmaf(r1[te], IL2f, -dv);
        const float l3 = fmaf(r3[te], IL2f, -dv);
        const int sl = 2 * tl;        // last blank
        a0 = (s0     == sl) ? lB : NEGV;
        a1 = (s0 + 1 == sl - 1) ? l1 : ((s0 + 1 == sl) ? lB : NEGV);
        a2 = (s0 + 2 == sl) ? lB : NEGV;
        a3 = (s0 + 3 == sl - 1) ? l3 : ((s0 + 3 == sl) ? lB : NEGV);
        // (odd s == sl impossible since sl even; kept simple & correct)
        if (s0 + 1 == sl - 1) a1 = l1; 
        if (s0 + 3 == sl - 1) a3 = l3;
    }

    if (!bwd) {
        const int tB = mid;                        // steps t = 1..mid
        const int gHi = tB >> 3;
        f4 B0 = LD4(rB), B1 = LD4(rB + 4), U0 = LD4(r1), U1 = LD4(r1 + 4),
           W0 = LD4(r3), W1 = LD4(r3 + 4), D0 = LD4(rD), D1 = LD4(rD + 4);
        f4 nB0, nB1, nU0, nU1, nW0, nW1, nD0, nD1;
        for (int g = 0; g <= gHi; ++g) {
            if (g < gHi) {
                const int b = (g + 1) * 8;
                nB0 = LD4(rB + b); nB1 = LD4(rB + b + 4);
                nU0 = LD4(r1 + b); nU1 = LD4(r1 + b + 4);
                nW0 = LD4(r3 + b); nW1 = LD4(r3 + b + 4);
                nD0 = LD4(rD + b); nD1 = LD4(rD + b + 4);
            }
            #pragma unroll
            for (int k = 0; k < 8; ++k) {
                const int t = g * 8 + k;
                if (t < 1 || t > tB) continue;               // block-uniform
                const float dv = E8(D0, D1, k);
                const float lB = fmaf(E8(B0, B1, k), IL2f, -dv);
                const float l1 = fmaf(E8(U0, U1, k), IL2f, -dv);
                const float l3 = fmaf(E8(W0, W1, k), IL2f, -dv);
                float u3 = wave_shr1(a3);                    // neighbor slot3 = s0-1
                u3 = lane ? u3 : NEGV;
                // slots 3,2 first: independent of the DPP result
                const float n3 = lse3_2(a3, a2, skip3f ? a1 : NEGV) + l3;
                const float n2 = lse2_2(a2, a1) + lB;
                const float n1 = lse3_2(a1, a0, skip1f ? u3 : NEGV) + l1;
                const float n0 = lse2_2(a0, u3) + lB;
                a0 = n0; a1 = n1; a2 = n2; a3 = n3;
            }
            if (g < gHi) { B0=nB0;B1=nB1;U0=nU0;U1=nU1;W0=nW0;W1=nW1;D0=nD0;D1=nD1; }
        }
    } else {
        const int tB = Tn - 2, tA = mid + 1;       // steps t = Tn-2 .. mid+1
        const int gHi = tB >> 3, gLo = tA >> 3;
        f4 B0 = LD4(rB + gHi * 8), B1 = LD4(rB + gHi * 8 + 4),
           U0 = LD4(r1 + gHi * 8), U1 = LD4(r1 + gHi * 8 + 4),
           W0 = LD4(r3 + gHi * 8), W1 = LD4(r3 + gHi * 8 + 4),
           D0 = LD4(rD + gHi * 8), D1 = LD4(rD + gHi * 8 + 4);
        f4 nB0, nB1, nU0, nU1, nW0, nW1, nD0, nD1;
        for (int g = gHi; g >= gLo; --g) {
            if (g > gLo) {
                const int b = (g - 1) * 8;
                nB0 = LD4(rB + b); nB1 = LD4(rB + b + 4);
                nU0 = LD4(r1 + b); nU1 = LD4(r1 + b + 4);
                nW0 = LD4(r3 + b); nW1 = LD4(r3 + b + 4);
                nD0 = LD4(rD + b); nD1 = LD4(rD + b + 4);
            }
            #pragma unroll
            for (int k = 7; k >= 0; --k) {
                const int t = g * 8 + k;
                if (t > tB || t < tA) continue;              // block-uniform
                const float dv = E8(D0, D1, k);
                const float lB = fmaf(E8(B0, B1, k), IL2f, -dv);
                const float l1 = fmaf(E8(U0, U1, k), IL2f, -dv);
                const float l3 = fmaf(E8(W0, W1, k), IL2f, -dv);
                float d0 = wave_shl1(a0);                    // neighbor slot0 = s0+4
                float d1 = wave_shl1(a1);                    // neighbor slot1 = s0+5
                d0 = (lane == 63) ? NEGV : d0;
                d1 = (lane == 63) ? NEGV : d1;
                // slots 0..2 first: independent of the DPP results
                const float n0 = lse2_2(a0, a1) + lB;
                const float n1 = lse3_2(a1, a2, skip1b ? a3 : NEGV) + l1;
                const float n2 = lse2_2(a2, a3) + lB;
                const float n3 = lse3_2(a3, d0, skip3b ? d1 : NEGV) + l3;
                a0 = n0; a1 = n1; a2 = n2; a3 = n3;
            }
            if (g > gLo) { B0=nB0;B1=nB1;U0=nU0;U1=nU1;W0=nW0;W1=nW1;D0=nD0;D1=nD1; }
        }
    }

    float* dst = (bwd ? wsB : wsA) + n * 256;
    f4 o;
    o[0] = (s0     < L) ? a0 : NEGV;
    o[1] = (s0 + 1 < L) ? a1 : NEGV;
    o[2] = (s0 + 2 < L) ? a2 : NEGV;
    o[3] = (s0 + 3 < L) ? a3 : NEGV;
    *(f4*)(dst + s0) = o;
}

// ---------------- Kernel 3: splice alpha*beta, lse over states, mean ----------------
__global__ __launch_bounds__(64) void ctc_combine_kernel(
    const float* __restrict__ wsA, const float* __restrict__ wsB,
    const int* __restrict__ targets, const int* __restrict__ tlen,
    float* __restrict__ out)
{
    const int n = blockIdx.x;
    const int lane = threadIdx.x;
    const int tl = tlen[n];
    const int L = 2 * tl + 1;
    float vals[4];
    float vmax = NEGV;
    #pragma unroll
    for (int k = 0; k < 4; ++k) {
        const int s = lane + (k << 6);
        float v = NEGV;
        if (s < L) {
            const float al = wsA[n * 256 + s];
            const float b0 = wsB[n * 256 + s];
            const float b1 = (s + 1 < L) ? wsB[n * 256 + s + 1] : NEGV;
            const bool skip = (s & 1) && (s + 2 < L) &&
                (targets[n * Ss + (s >> 1) + 1] != targets[n * Ss + (s >> 1)]);
            const float b2 = skip ? wsB[n * 256 + s + 2] : NEGV;
            const float m3 = fmaxf(fmaxf(b0, b1), b2);
            const float B = m3 + log2_hw(exp2_hw(b0 - m3) + exp2_hw(b1 - m3) + exp2_hw(b2 - m3));
            v = al + B;
        }
        vals[k] = v;
        vmax = fmaxf(vmax, v);
    }
    #pragma unroll
    for (int o = 32; o; o >>= 1) vmax = fmaxf(vmax, __shfl_xor(vmax, o));
    float ssum = 0.f;
    #pragma unroll
    for (int k = 0; k < 4; ++k) ssum += exp2_hw(vals[k] - vmax);
    #pragma unroll
    for (int o = 32; o; o >>= 1) ssum += __shfl_xor(ssum, o);
    if (lane == 0) {
        const float total2 = vmax + log2_hw(ssum);
        const float loss = -LN2f * total2;                  // back to natural log
        atomicAdd(out, loss / ((float)tl * (float)Nn));
    }
}

extern "C" void kernel_launch(void* const* d_in, const int* in_sizes, int n_in,
                              void* d_out, int out_size, void* d_ws, size_t ws_size,
                              hipStream_t stream) {
    const float* logits = (const float*)d_in[0];
    const int* targets  = (const int*)d_in[1];
    const int* tlen     = (const int*)d_in[2];
    const int* ilen     = (const int*)d_in[3];
    float* out = (float*)d_out;

    float* wsA = (float*)d_ws;            // 64*256 floats: alpha at t=mid
    float* wsB = wsA + Nn * 256;          // 64*256 floats: beta  at t=mid+1
    float* d2  = wsB + Nn * 256;          // 64*4000 floats: log2-softmax denominators

    hipMemsetAsync(d_out, 0, sizeof(float), stream);
    ctc_denom_kernel<<<dim3(4, Nn), 256, 0, stream>>>(logits, d2);
    ctc_fb_kernel<<<Nn * 2, 64, 0, stream>>>(logits, targets, tlen, ilen, d2, wsA, wsB);
    ctc_combine_kernel<<<Nn, 64, 0, stream>>>(wsA, wsB, targets, tlen, out);
}

// Round 5
// 261.247 us; speedup vs baseline: 2.0368x; 1.3148x over previous
//
#include <hip/hip_runtime.h>
#include <cstdint>
#include <cstddef>

#define NEGV (-1e30f)
#define IL2f 1.44269504088896340736f
#define LN2f 0.693147180559945309417f

__device__ __forceinline__ float exp2_hw(float x) { return __builtin_amdgcn_exp2f(x); }
__device__ __forceinline__ float log2_hw(float x) { return __builtin_amdgcn_logf(x); }

constexpr int Nn = 64, Cc = 64, Tt = 4000, Ss = 100;

// Full-wave lane shifts via DPP; bound_ctrl=true => shifted-in lanes read 0.
__device__ __forceinline__ float wave_shr1(float x) {  // lane n <- lane n-1
    return __int_as_float(__builtin_amdgcn_update_dpp(0, __float_as_int(x), 0x138, 0xF, 0xF, true));
}
__device__ __forceinline__ float wave_shl1(float x) {  // lane n <- lane n+1
    return __int_as_float(__builtin_amdgcn_update_dpp(0, __float_as_int(x), 0x130, 0xF, 0xF, true));
}
__device__ __forceinline__ int wave_shr1_i(int x) {
    return __builtin_amdgcn_update_dpp(0, x, 0x138, 0xF, 0xF, true);
}
__device__ __forceinline__ int wave_shl1_i(int x) {
    return __builtin_amdgcn_update_dpp(0, x, 0x130, 0xF, 0xF, true);
}

typedef float f4 __attribute__((ext_vector_type(4)));
#define LD4(p) (*(const f4*)(p))
#define E8(a0, a1, k) ((k) < 4 ? (a0)[(k)] : (a1)[(k) - 4])

// ---------------- Kernel 1a: per-(n,t) log2-softmax denominator ----------------
__global__ __launch_bounds__(256) void ctc_denom_kernel(
    const float* __restrict__ logits, float* __restrict__ d2)
{
    const int t4 = (blockIdx.x * 256 + threadIdx.x) * 4;
    const int n = blockIdx.y;
    if (t4 >= Tt) return;
    const float* __restrict__ p = logits + (size_t)n * Cc * Tt + t4;
    f4 m, s;
    {
        f4 v = LD4(p);
        #pragma unroll
        for (int i = 0; i < 4; ++i) { m[i] = v[i] * IL2f; s[i] = 1.f; }
    }
    #pragma unroll 4
    for (int c = 1; c < Cc; ++c) {
        f4 v = LD4(p + (size_t)c * Tt);
        #pragma unroll
        for (int i = 0; i < 4; ++i) {
            float vi = v[i] * IL2f;
            float nm = fmaxf(m[i], vi);
            s[i] = s[i] * exp2_hw(m[i] - nm) + exp2_hw(vi - nm);
            m[i] = nm;
        }
    }
    f4 o;
    #pragma unroll
    for (int i = 0; i < 4; ++i) o[i] = m[i] + log2_hw(s[i]);
    *(f4*)(d2 + (size_t)n * Tt + t4) = o;
}

// ---------------- Kernel 1b: softmax probabilities P = exp2(l*IL2 - d2) ----------------
__global__ __launch_bounds__(256) void ctc_prob_kernel(
    const float* __restrict__ logits, const float* __restrict__ d2, float* __restrict__ P)
{
    const int t4 = (blockIdx.x * 256 + threadIdx.x) * 4;
    const int n = blockIdx.y;
    const int c0 = blockIdx.z * 8;
    if (t4 >= Tt) return;
    const f4 d = LD4(d2 + (size_t)n * Tt + t4);
    const float* __restrict__ src = logits + ((size_t)n * Cc + c0) * Tt + t4;
    float* __restrict__ dst = P + ((size_t)n * Cc + c0) * Tt + t4;
    #pragma unroll
    for (int c = 0; c < 8; ++c) {
        f4 v = LD4(src + (size_t)c * Tt);
        f4 o;
        #pragma unroll
        for (int i = 0; i < 4; ++i) o[i] = exp2_hw(fmaf(v[i], IL2f, -d[i]));
        *(f4*)(dst + (size_t)c * Tt) = o;
    }
}

// ---------------- Kernel 2: fwd/bwd recurrence, linear domain, PER-LANE exponent ----
// blockIdx.x = 2*n + dir. 64 threads = 1 wave; lane owns states s = 4*lane + k.
// Each lane: 4 f32 mantissas (renormed to lane max in [1,2) every step) + int E.
// Cross-lane values reconciled via 2^(E_nbr - E); massless lanes adopt neighbor E.
template<bool PRE>
__global__ __launch_bounds__(64) void ctc_fb_kernel(
    const float* __restrict__ PR, const int* __restrict__ targets,
    const int* __restrict__ tlen, const int* __restrict__ ilen,
    const float* __restrict__ d2, float* __restrict__ wsA, float* __restrict__ wsB)
{
    const int bid = blockIdx.x;
    const int n = bid >> 1;
    const bool bwd = bid & 1;
    const int lane = threadIdx.x;
    const int tl = tlen[n];
    const int Tn = ilen[n];
    const int L = 2 * tl + 1;
    const int mid = Tn >> 1;
    const int s0 = 4 * lane;

    const int j1 = min(2 * lane, Ss - 1);
    const int j3 = min(2 * lane + 1, Ss - 1);
    const int base = n * Ss;
    const int tg1 = targets[base + j1];
    const int tg3 = targets[base + j3];
    const int tg1m = targets[base + max(2 * lane - 1, 0)];
    const int tg3p = targets[base + min(2 * lane + 2, Ss - 1)];

    const float sk1f = ((s0 + 1 >= 3) && (tg1 != tg1m)) ? 1.f : 0.f;
    const float sk3f = (tg3 != tg1) ? 1.f : 0.f;
    const float sk1b = ((s0 + 3 < L) && (tg3 != tg1)) ? 1.f : 0.f;
    const float sk3b = ((s0 + 5 < L) && (tg3p != tg3)) ? 1.f : 0.f;

    const float* __restrict__ rB = PR + (size_t)(n * Cc) * Tt;
    const float* __restrict__ r1 = PR + (size_t)(n * Cc + tg1) * Tt;
    const float* __restrict__ r3 = PR + (size_t)(n * Cc + tg3) * Tt;
    const float* __restrict__ rD = d2 + (size_t)n * Tt;

    float a0, a1, a2, a3;
    int E = 0;

    if (!bwd) {
        float pB0, p10;
        if constexpr (PRE) { pB0 = rB[0]; p10 = r1[0]; }
        else {
            const float dv = rD[0];
            pB0 = exp2_hw(fmaf(rB[0], IL2f, -dv));
            p10 = exp2_hw(fmaf(r1[0], IL2f, -dv));
        }
        a0 = (lane == 0) ? pB0 : 0.f;
        a1 = (lane == 0) ? p10 : 0.f;
        a2 = 0.f; a3 = 0.f;
    } else {
        const int te = Tn - 1;
        float pBe, p1e, p3e;
        if constexpr (PRE) { pBe = rB[te]; p1e = r1[te]; p3e = r3[te]; }
        else {
            const float dv = rD[te];
            pBe = exp2_hw(fmaf(rB[te], IL2f, -dv));
            p1e = exp2_hw(fmaf(r1[te], IL2f, -dv));
            p3e = exp2_hw(fmaf(r3[te], IL2f, -dv));
        }
        const int sl = 2 * tl;
        a0 = (s0 == sl) ? pBe : 0.f;
        a1 = (s0 + 1 == sl - 1) ? p1e : 0.f;
        a2 = (s0 + 2 == sl) ? pBe : 0.f;
        a3 = (s0 + 3 == sl - 1) ? p3e : 0.f;
    }

    if (!bwd) {
        const int tB = mid;                  // steps t = 1..mid
        const int gHi = tB >> 3;
        f4 B0 = LD4(rB), B1 = LD4(rB + 4), U0 = LD4(r1), U1 = LD4(r1 + 4),
           W0 = LD4(r3), W1 = LD4(r3 + 4);
        f4 D0 = {}, D1 = {};
        if constexpr (!PRE) { D0 = LD4(rD); D1 = LD4(rD + 4); }
        f4 nB0, nB1, nU0, nU1, nW0, nW1, nD0, nD1;
        for (int g = 0; g <= gHi; ++g) {
            if (g < gHi) {
                const int b = (g + 1) * 8;
                nB0 = LD4(rB + b); nB1 = LD4(rB + b + 4);
                nU0 = LD4(r1 + b); nU1 = LD4(r1 + b + 4);
                nW0 = LD4(r3 + b); nW1 = LD4(r3 + b + 4);
                if constexpr (!PRE) { nD0 = LD4(rD + b); nD1 = LD4(rD + b + 4); }
            }
            #pragma unroll
            for (int k = 0; k < 8; ++k) {
                const int t = g * 8 + k;
                if (t < 1 || t > tB) continue;             // block-uniform
                float pB, p1, p3;
                if constexpr (PRE) {
                    pB = E8(B0, B1, k); p1 = E8(U0, U1, k); p3 = E8(W0, W1, k);
                } else {
                    const float dv = E8(D0, D1, k);
                    pB = exp2_hw(fmaf(E8(B0, B1, k), IL2f, -dv));
                    p1 = exp2_hw(fmaf(E8(U0, U1, k), IL2f, -dv));
                    p3 = exp2_hw(fmaf(E8(W0, W1, k), IL2f, -dv));
                }
                const float u3 = wave_shr1(a3);            // neighbor slot3 mantissa
                const int   Eu = wave_shr1_i(E);           // neighbor exponent
                const int   eb = min(max(127 + (Eu - E), 0), 230);
                const float sc = __int_as_float((unsigned)eb << 23);
                const float u3s = u3 * sc;                 // in our base now
                const float n3 = fmaf(a1, sk3f, a3 + a2) * p3;
                const float n2 = (a2 + a1) * pB;
                const float n1 = fmaf(u3s, sk1f, a1 + a0) * p1;
                const float n0 = (a0 + u3s) * pB;
                // per-lane renorm: lane max -> [1,2), fold into E
                const float mx = fmaxf(fmaxf(n0, n1), fmaxf(n2, n3));
                const int   me = (int)(__float_as_uint(mx) >> 23);
                const float sc2 = __int_as_float((unsigned)(254 - me) << 23);
                a0 = n0 * sc2; a1 = n1 * sc2; a2 = n2 * sc2; a3 = n3 * sc2;
                E = (mx > 0.f) ? (E + me - 127) : Eu;      // massless: adopt upstream base
            }
            if (g < gHi) {
                B0=nB0;B1=nB1;U0=nU0;U1=nU1;W0=nW0;W1=nW1;
                if constexpr (!PRE) { D0=nD0;D1=nD1; }
            }
        }
    } else {
        const int tB = Tn - 2, tA = mid + 1; // steps t = Tn-2 .. mid+1 (descending)
        const int gHi = tB >> 3, gLo = tA >> 3;
        f4 B0 = LD4(rB + gHi * 8), B1 = LD4(rB + gHi * 8 + 4),
           U0 = LD4(r1 + gHi * 8), U1 = LD4(r1 + gHi * 8 + 4),
           W0 = LD4(r3 + gHi * 8), W1 = LD4(r3 + gHi * 8 + 4);
        f4 D0 = {}, D1 = {};
        if constexpr (!PRE) { D0 = LD4(rD + gHi * 8); D1 = LD4(rD + gHi * 8 + 4); }
        f4 nB0, nB1, nU0, nU1, nW0, nW1, nD0, nD1;
        for (int g = gHi; g >= gLo; --g) {
            if (g > gLo) {
                const int b = (g - 1) * 8;
                nB0 = LD4(rB + b); nB1 = LD4(rB + b + 4);
                nU0 = LD4(r1 + b); nU1 = LD4(r1 + b + 4);
                nW0 = LD4(r3 + b); nW1 = LD4(r3 + b + 4);
                if constexpr (!PRE) { nD0 = LD4(rD + b); nD1 = LD4(rD + b + 4); }
            }
            #pragma unroll
            for (int k = 7; k >= 0; --k) {
                const int t = g * 8 + k;
                if (t > tB || t < tA) continue;            // block-uniform
                float pB, p1, p3;
                if constexpr (PRE) {
                    pB = E8(B0, B1, k); p1 = E8(U0, U1, k); p3 = E8(W0, W1, k);
                } else {
                    const float dv = E8(D0, D1, k);
                    pB = exp2_hw(fmaf(E8(B0, B1, k), IL2f, -dv));
                    p1 = exp2_hw(fmaf(E8(U0, U1, k), IL2f, -dv));
                    p3 = exp2_hw(fmaf(E8(W0, W1, k), IL2f, -dv));
                }
                const float d0 = wave_shl1(a0);
                const float d1 = wave_shl1(a1);
                const int   Ed = wave_shl1_i(E);
                const int   eb = min(max(127 + (Ed - E), 0), 230);
                const float sc = __int_as_float((unsigned)eb << 23);
                const float d0s = d0 * sc;
                const float d1s = d1 * sc;
                const float n0 = (a0 + a1) * pB;
                const float n1 = fmaf(a3, sk1b, a1 + a2) * p1;
                const float n2 = (a2 + a3) * pB;
                const float n3 = fmaf(d1s, sk3b, a3 + d0s) * p3;
                const float mx = fmaxf(fmaxf(n0, n1), fmaxf(n2, n3));
                const int   me = (int)(__float_as_uint(mx) >> 23);
                const float sc2 = __int_as_float((unsigned)(254 - me) << 23);
                a0 = n0 * sc2; a1 = n1 * sc2; a2 = n2 * sc2; a3 = n3 * sc2;
                E = (mx > 0.f) ? (E + me - 127) : Ed;      // massless: adopt downstream base
            }
            if (g > gLo) {
                B0=nB0;B1=nB1;U0=nU0;U1=nU1;W0=nW0;W1=nW1;
                if constexpr (!PRE) { D0=nD0;D1=nD1; }
            }
        }
    }

    // convert to log2 domain for the combine kernel
    float* dst = (bwd ? wsB : wsA) + n * 256;
    const float Ef = (float)E;
    f4 o;
    o[0] = (s0     < L && a0 > 0.f) ? log2_hw(a0) + Ef : NEGV;
    o[1] = (s0 + 1 < L && a1 > 0.f) ? log2_hw(a1) + Ef : NEGV;
    o[2] = (s0 + 2 < L && a2 > 0.f) ? log2_hw(a2) + Ef : NEGV;
    o[3] = (s0 + 3 < L && a3 > 0.f) ? log2_hw(a3) + Ef : NEGV;
    *(f4*)(dst + s0) = o;
}

// ---------------- Kernel 3: splice alpha*beta, lse over states, mean ----------------
__global__ __launch_bounds__(64) void ctc_combine_kernel(
    const float* __restrict__ wsA, const float* __restrict__ wsB,
    const int* __restrict__ targets, const int* __restrict__ tlen,
    float* __restrict__ out)
{
    const int n = blockIdx.x;
    const int lane = threadIdx.x;
    const int tl = tlen[n];
    const int L = 2 * tl + 1;
    float vals[4];
    float vmax = NEGV;
    #pragma unroll
    for (int k = 0; k < 4; ++k) {
        const int s = lane + (k << 6);
        float v = NEGV;
        if (s < L) {
            const float al = wsA[n * 256 + s];
            const float b0 = wsB[n * 256 + s];
            const float b1 = (s + 1 < L) ? wsB[n * 256 + s + 1] : NEGV;
            const bool skip = (s & 1) && (s + 2 < L) &&
                (targets[n * Ss + (s >> 1) + 1] != targets[n * Ss + (s >> 1)]);
            const float b2 = skip ? wsB[n * 256 + s + 2] : NEGV;
            const float m3 = fmaxf(fmaxf(b0, b1), b2);
            const float B = m3 + log2_hw(exp2_hw(b0 - m3) + exp2_hw(b1 - m3) + exp2_hw(b2 - m3));
            v = al + B;
        }
        vals[k] = v;
        vmax = fmaxf(vmax, v);
    }
    #pragma unroll
    for (int o = 32; o; o >>= 1) vmax = fmaxf(vmax, __shfl_xor(vmax, o));
    float ssum = 0.f;
    #pragma unroll
    for (int k = 0; k < 4; ++k) ssum += exp2_hw(vals[k] - vmax);
    #pragma unroll
    for (int o = 32; o; o >>= 1) ssum += __shfl_xor(ssum, o);
    if (lane == 0) {
        const float total2 = vmax + log2_hw(ssum);
        const float loss = -LN2f * total2;
        atomicAdd(out, loss / ((float)tl * (float)Nn));
    }
}

extern "C" void kernel_launch(void* const* d_in, const int* in_sizes, int n_in,
                              void* d_out, int out_size, void* d_ws, size_t ws_size,
                              hipStream_t stream) {
    const float* logits = (const float*)d_in[0];
    const int* targets  = (const int*)d_in[1];
    const int* tlen     = (const int*)d_in[2];
    const int* ilen     = (const int*)d_in[3];
    float* out = (float*)d_out;

    float* wsA = (float*)d_ws;                     // 64*256
    float* wsB = wsA + Nn * 256;                   // 64*256
    float* d2  = wsB + Nn * 256;                   // 64*4000
    float* P   = d2 + (size_t)Nn * Tt;             // 64*64*4000 (if it fits)
    const size_t need = ((size_t)Nn * 256 * 2 + (size_t)Nn * Tt
                         + (size_t)Nn * Cc * Tt) * sizeof(float);

    hipMemsetAsync(d_out, 0, sizeof(float), stream);
    ctc_denom_kernel<<<dim3(4, Nn), 256, 0, stream>>>(logits, d2);
    if (ws_size >= need) {
        ctc_prob_kernel<<<dim3(4, Nn, 8), 256, 0, stream>>>(logits, d2, P);
        ctc_fb_kernel<true><<<Nn * 2, 64, 0, stream>>>(P, targets, tlen, ilen, d2, wsA, wsB);
    } else {
        ctc_fb_kernel<false><<<Nn * 2, 64, 0, stream>>>(logits, targets, tlen, ilen, d2, wsA, wsB);
    }
    ctc_combine_kernel<<<Nn, 64, 0, stream>>>(wsA, wsB, targets, tlen, out);
}

// Round 6
// 233.923 us; speedup vs baseline: 2.2748x; 1.1168x over previous
//
#include <hip/hip_runtime.h>
#include <cstdint>
#include <cstddef>

#define NEGV (-1e30f)
#define IL2f 1.44269504088896340736f
#define LN2f 0.693147180559945309417f

__device__ __forceinline__ float exp2_hw(float x) { return __builtin_amdgcn_exp2f(x); }
__device__ __forceinline__ float log2_hw(float x) { return __builtin_amdgcn_logf(x); }

constexpr int Nn = 64, Cc = 64, Tt = 4000, Ss = 100;

// Full-wave lane shifts via DPP; bound_ctrl=true => shifted-in lanes read 0.
__device__ __forceinline__ float wave_shr1(float x) {  // lane n <- lane n-1
    return __int_as_float(__builtin_amdgcn_update_dpp(0, __float_as_int(x), 0x138, 0xF, 0xF, true));
}
__device__ __forceinline__ float wave_shl1(float x) {  // lane n <- lane n+1
    return __int_as_float(__builtin_amdgcn_update_dpp(0, __float_as_int(x), 0x130, 0xF, 0xF, true));
}
__device__ __forceinline__ int wave_shr1_i(int x) {
    return __builtin_amdgcn_update_dpp(0, x, 0x138, 0xF, 0xF, true);
}
__device__ __forceinline__ int wave_shl1_i(int x) {
    return __builtin_amdgcn_update_dpp(0, x, 0x130, 0xF, 0xF, true);
}

typedef float f4 __attribute__((ext_vector_type(4)));
#define LD4(p) (*(const f4*)(p))
#define E8(a0, a1, k) ((k) < 4 ? (a0)[(k)] : (a1)[(k) - 4])

// -------- Kernel 1: fused per-(n,t) log2-softmax denominator + probabilities --------
// Pass 1: online max/sum over C -> d (kept in registers). Pass 2 (if P): re-read
// logits (L2-hot) and write P = exp2(l*IL2 - d). d2 always written (for !PRE fb).
__global__ __launch_bounds__(256) void ctc_softmax_kernel(
    const float* __restrict__ logits, float* __restrict__ d2, float* __restrict__ P)
{
    const int t4 = (blockIdx.x * 256 + threadIdx.x) * 4;
    const int n = blockIdx.y;
    if (t4 >= Tt) return;
    const float* __restrict__ p = logits + (size_t)n * Cc * Tt + t4;
    f4 m, s;
    {
        f4 v = LD4(p);
        #pragma unroll
        for (int i = 0; i < 4; ++i) { m[i] = v[i] * IL2f; s[i] = 1.f; }
    }
    #pragma unroll 4
    for (int c = 1; c < Cc; ++c) {
        f4 v = LD4(p + (size_t)c * Tt);
        #pragma unroll
        for (int i = 0; i < 4; ++i) {
            float vi = v[i] * IL2f;
            float nm = fmaxf(m[i], vi);
            s[i] = s[i] * exp2_hw(m[i] - nm) + exp2_hw(vi - nm);
            m[i] = nm;
        }
    }
    f4 d;
    #pragma unroll
    for (int i = 0; i < 4; ++i) d[i] = m[i] + log2_hw(s[i]);
    *(f4*)(d2 + (size_t)n * Tt + t4) = d;
    if (P) {
        float* __restrict__ dst = P + (size_t)n * Cc * Tt + t4;
        #pragma unroll 4
        for (int c = 0; c < Cc; ++c) {
            f4 v = LD4(p + (size_t)c * Tt);
            f4 o;
            #pragma unroll
            for (int i = 0; i < 4; ++i) o[i] = exp2_hw(fmaf(v[i], IL2f, -d[i]));
            *(f4*)(dst + (size_t)c * Tt) = o;
        }
    }
}

// ---------------- Kernel 2: fwd/bwd recurrence, linear domain, PER-LANE exponent ----
// blockIdx.x = 2*n + dir. 64 threads = 1 wave; lane owns states s = 4*lane + k.
// Per-lane exponent E; renorm + cross-lane E reconcile hoisted to every-2-step
// windows; reconcile scale folded into window constants so the per-step chain is
// DPP -> fmaf -> mul. Massless lanes adopt the neighbor E at each window end
// (adoption front == mass front at 1 lane / 2 steps; mismatch << 126-bit flush).
template<bool PRE>
__global__ __launch_bounds__(64) void ctc_fb_kernel(
    const float* __restrict__ PR, const int* __restrict__ targets,
    const int* __restrict__ tlen, const int* __restrict__ ilen,
    const float* __restrict__ d2, float* __restrict__ wsA, float* __restrict__ wsB)
{
    const int bid = blockIdx.x;
    const int n = bid >> 1;
    const bool bwd = bid & 1;
    const int lane = threadIdx.x;
    const int tl = tlen[n];
    const int Tn = ilen[n];
    const int L = 2 * tl + 1;
    const int mid = Tn >> 1;
    const int s0 = 4 * lane;

    const int j1 = min(2 * lane, Ss - 1);
    const int j3 = min(2 * lane + 1, Ss - 1);
    const int base = n * Ss;
    const int tg1 = targets[base + j1];
    const int tg3 = targets[base + j3];
    const int tg1m = targets[base + max(2 * lane - 1, 0)];
    const int tg3p = targets[base + min(2 * lane + 2, Ss - 1)];

    const float sk1f = ((s0 + 1 >= 3) && (tg1 != tg1m)) ? 1.f : 0.f;
    const float sk3f = (tg3 != tg1) ? 1.f : 0.f;
    const float sk1b = ((s0 + 3 < L) && (tg3 != tg1)) ? 1.f : 0.f;
    const float sk3b = ((s0 + 5 < L) && (tg3p != tg3)) ? 1.f : 0.f;

    const float* __restrict__ rB = PR + (size_t)(n * Cc) * Tt;
    const float* __restrict__ r1 = PR + (size_t)(n * Cc + tg1) * Tt;
    const float* __restrict__ r3 = PR + (size_t)(n * Cc + tg3) * Tt;
    const float* __restrict__ rD = d2 + (size_t)n * Tt;

    float a0, a1, a2, a3;
    int E = 0;

    if (!bwd) {
        float pB0, p10;
        if constexpr (PRE) { pB0 = rB[0]; p10 = r1[0]; }
        else {
            const float dv = rD[0];
            pB0 = exp2_hw(fmaf(rB[0], IL2f, -dv));
            p10 = exp2_hw(fmaf(r1[0], IL2f, -dv));
        }
        a0 = (lane == 0) ? pB0 : 0.f;
        a1 = (lane == 0) ? p10 : 0.f;
        a2 = 0.f; a3 = 0.f;
    } else {
        const int te = Tn - 1;
        float pBe, p1e, p3e;
        if constexpr (PRE) { pBe = rB[te]; p1e = r1[te]; p3e = r3[te]; }
        else {
            const float dv = rD[te];
            pBe = exp2_hw(fmaf(rB[te], IL2f, -dv));
            p1e = exp2_hw(fmaf(r1[te], IL2f, -dv));
            p3e = exp2_hw(fmaf(r3[te], IL2f, -dv));
        }
        const int sl = 2 * tl;
        a0 = (s0 == sl) ? pBe : 0.f;
        a1 = (s0 + 1 == sl - 1) ? p1e : 0.f;
        a2 = (s0 + 2 == sl) ? pBe : 0.f;
        a3 = (s0 + 3 == sl - 1) ? p3e : 0.f;
    }

    if (!bwd) {
        const int tB = mid;                  // steps t = 1..mid
        const int gHi = tB >> 3;
        f4 B0 = LD4(rB), B1 = LD4(rB + 4), U0 = LD4(r1), U1 = LD4(r1 + 4),
           W0 = LD4(r3), W1 = LD4(r3 + 4);
        f4 D0 = {}, D1 = {};
        if constexpr (!PRE) { D0 = LD4(rD); D1 = LD4(rD + 4); }
        f4 nB0, nB1, nU0, nU1, nW0, nW1, nD0, nD1;
        for (int g = 0; g <= gHi; ++g) {
            if (g < gHi) {
                const int b = (g + 1) * 8;
                nB0 = LD4(rB + b); nB1 = LD4(rB + b + 4);
                nU0 = LD4(r1 + b); nU1 = LD4(r1 + b + 4);
                nW0 = LD4(r3 + b); nW1 = LD4(r3 + b + 4);
                if constexpr (!PRE) { nD0 = LD4(rD + b); nD1 = LD4(rD + b + 4); }
            }
            #pragma unroll
            for (int w = 0; w < 4; ++w) {
                // ---- window setup: cross-lane E reconcile, folded into constants ----
                const int   Eu = wave_shr1_i(E);
                const int   eb = min(max(127 + (Eu - E), 0), 230);
                const float sc = __int_as_float((unsigned)eb << 23);
                const float sk1fs = sk1f * sc;
                #pragma unroll
                for (int kk = 0; kk < 2; ++kk) {
                    const int k = w * 2 + kk;
                    const int t = g * 8 + k;
                    if (t < 1 || t > tB) continue;         // block-uniform
                    float pB, p1, p3;
                    if constexpr (PRE) {
                        pB = E8(B0, B1, k); p1 = E8(U0, U1, k); p3 = E8(W0, W1, k);
                    } else {
                        const float dv = E8(D0, D1, k);
                        pB = exp2_hw(fmaf(E8(B0, B1, k), IL2f, -dv));
                        p1 = exp2_hw(fmaf(E8(U0, U1, k), IL2f, -dv));
                        p3 = exp2_hw(fmaf(E8(W0, W1, k), IL2f, -dv));
                    }
                    const float u3 = wave_shr1(a3);
                    const float n3 = fmaf(a1, sk3f, a3 + a2) * p3;
                    const float n2 = (a2 + a1) * pB;
                    const float n1 = fmaf(u3, sk1fs, a1 + a0) * p1;
                    const float n0 = fmaf(u3, sc, a0) * pB;
                    a0 = n0; a1 = n1; a2 = n2; a3 = n3;
                }
                // ---- window end: per-lane renorm to [1,2), adopt E if massless ----
                const float mx = fmaxf(fmaxf(a0, a1), fmaxf(a2, a3));
                const int   me = (int)(__float_as_uint(mx) >> 23);
                const float sc2 = __int_as_float((unsigned)(254 - me) << 23);
                a0 *= sc2; a1 *= sc2; a2 *= sc2; a3 *= sc2;
                E = (mx > 0.f) ? (E + me - 127) : Eu;
            }
            if (g < gHi) {
                B0=nB0;B1=nB1;U0=nU0;U1=nU1;W0=nW0;W1=nW1;
                if constexpr (!PRE) { D0=nD0;D1=nD1; }
            }
        }
    } else {
        const int tB = Tn - 2, tA = mid + 1; // steps t = Tn-2 .. mid+1 (descending)
        const int gHi = tB >> 3, gLo = tA >> 3;
        f4 B0 = LD4(rB + gHi * 8), B1 = LD4(rB + gHi * 8 + 4),
           U0 = LD4(r1 + gHi * 8), U1 = LD4(r1 + gHi * 8 + 4),
           W0 = LD4(r3 + gHi * 8), W1 = LD4(r3 + gHi * 8 + 4);
        f4 D0 = {}, D1 = {};
        if constexpr (!PRE) { D0 = LD4(rD + gHi * 8); D1 = LD4(rD + gHi * 8 + 4); }
        f4 nB0, nB1, nU0, nU1, nW0, nW1, nD0, nD1;
        for (int g = gHi; g >= gLo; --g) {
            if (g > gLo) {
                const int b = (g - 1) * 8;
                nB0 = LD4(rB + b); nB1 = LD4(rB + b + 4);
                nU0 = LD4(r1 + b); nU1 = LD4(r1 + b + 4);
                nW0 = LD4(r3 + b); nW1 = LD4(r3 + b + 4);
                if constexpr (!PRE) { nD0 = LD4(rD + b); nD1 = LD4(rD + b + 4); }
            }
            #pragma unroll
            for (int w = 3; w >= 0; --w) {
                const int   Ed = wave_shl1_i(E);
                const int   eb = min(max(127 + (Ed - E), 0), 230);
                const float sc = __int_as_float((unsigned)eb << 23);
                const float sk3bs = sk3b * sc;
                #pragma unroll
                for (int kk = 1; kk >= 0; --kk) {
                    const int k = w * 2 + kk;
                    const int t = g * 8 + k;
                    if (t > tB || t < tA) continue;        // block-uniform
                    float pB, p1, p3;
                    if constexpr (PRE) {
                        pB = E8(B0, B1, k); p1 = E8(U0, U1, k); p3 = E8(W0, W1, k);
                    } else {
                        const float dv = E8(D0, D1, k);
                        pB = exp2_hw(fmaf(E8(B0, B1, k), IL2f, -dv));
                        p1 = exp2_hw(fmaf(E8(U0, U1, k), IL2f, -dv));
                        p3 = exp2_hw(fmaf(E8(W0, W1, k), IL2f, -dv));
                    }
                    const float d0 = wave_shl1(a0);
                    const float d1 = wave_shl1(a1);
                    const float n0 = (a0 + a1) * pB;
                    const float n1 = fmaf(a3, sk1b, a1 + a2) * p1;
                    const float n2 = (a2 + a3) * pB;
                    const float n3 = fmaf(d1, sk3bs, fmaf(d0, sc, a3)) * p3;
                    a0 = n0; a1 = n1; a2 = n2; a3 = n3;
                }
                const float mx = fmaxf(fmaxf(a0, a1), fmaxf(a2, a3));
                const int   me = (int)(__float_as_uint(mx) >> 23);
                const float sc2 = __int_as_float((unsigned)(254 - me) << 23);
                a0 *= sc2; a1 *= sc2; a2 *= sc2; a3 *= sc2;
                E = (mx > 0.f) ? (E + me - 127) : Ed;
            }
            if (g > gLo) {
                B0=nB0;B1=nB1;U0=nU0;U1=nU1;W0=nW0;W1=nW1;
                if constexpr (!PRE) { D0=nD0;D1=nD1; }
            }
        }
    }

    // convert to log2 domain for the combine kernel
    float* dst = (bwd ? wsB : wsA) + n * 256;
    const float Ef = (float)E;
    f4 o;
    o[0] = (s0     < L && a0 > 0.f) ? log2_hw(a0) + Ef : NEGV;
    o[1] = (s0 + 1 < L && a1 > 0.f) ? log2_hw(a1) + Ef : NEGV;
    o[2] = (s0 + 2 < L && a2 > 0.f) ? log2_hw(a2) + Ef : NEGV;
    o[3] = (s0 + 3 < L && a3 > 0.f) ? log2_hw(a3) + Ef : NEGV;
    *(f4*)(dst + s0) = o;
}

// ---------------- Kernel 3: splice alpha*beta, lse over states, mean ----------------
__global__ __launch_bounds__(64) void ctc_combine_kernel(
    const float* __restrict__ wsA, const float* __restrict__ wsB,
    const int* __restrict__ targets, const int* __restrict__ tlen,
    float* __restrict__ out)
{
    const int n = blockIdx.x;
    const int lane = threadIdx.x;
    const int tl = tlen[n];
    const int L = 2 * tl + 1;
    float vals[4];
    float vmax = NEGV;
    #pragma unroll
    for (int k = 0; k < 4; ++k) {
        const int s = lane + (k << 6);
        float v = NEGV;
        if (s < L) {
            const float al = wsA[n * 256 + s];
            const float b0 = wsB[n * 256 + s];
            const float b1 = (s + 1 < L) ? wsB[n * 256 + s + 1] : NEGV;
            const bool skip = (s & 1) && (s + 2 < L) &&
                (targets[n * Ss + (s >> 1) + 1] != targets[n * Ss + (s >> 1)]);
            const float b2 = skip ? wsB[n * 256 + s + 2] : NEGV;
            const float m3 = fmaxf(fmaxf(b0, b1), b2);
            const float B = m3 + log2_hw(exp2_hw(b0 - m3) + exp2_hw(b1 - m3) + exp2_hw(b2 - m3));
            v = al + B;
        }
        vals[k] = v;
        vmax = fmaxf(vmax, v);
    }
    #pragma unroll
    for (int o = 32; o; o >>= 1) vmax = fmaxf(vmax, __shfl_xor(vmax, o));
    float ssum = 0.f;
    #pragma unroll
    for (int k = 0; k < 4; ++k) ssum += exp2_hw(vals[k] - vmax);
    #pragma unroll
    for (int o = 32; o; o >>= 1) ssum += __shfl_xor(ssum, o);
    if (lane == 0) {
        const float total2 = vmax + log2_hw(ssum);
        const float loss = -LN2f * total2;
        atomicAdd(out, loss / ((float)tl * (float)Nn));
    }
}

extern "C" void kernel_launch(void* const* d_in, const int* in_sizes, int n_in,
                              void* d_out, int out_size, void* d_ws, size_t ws_size,
                              hipStream_t stream) {
    const float* logits = (const float*)d_in[0];
    const int* targets  = (const int*)d_in[1];
    const int* tlen     = (const int*)d_in[2];
    const int* ilen     = (const int*)d_in[3];
    float* out = (float*)d_out;

    float* wsA = (float*)d_ws;                     // 64*256
    float* wsB = wsA + Nn * 256;                   // 64*256
    float* d2  = wsB + Nn * 256;                   // 64*4000
    float* P   = d2 + (size_t)Nn * Tt;             // 64*64*4000 (if it fits)
    const size_t need = ((size_t)Nn * 256 * 2 + (size_t)Nn * Tt
                         + (size_t)Nn * Cc * Tt) * sizeof(float);
    const bool pre = (ws_size >= need);

    hipMemsetAsync(d_out, 0, sizeof(float), stream);
    ctc_softmax_kernel<<<dim3(4, Nn), 256, 0, stream>>>(logits, d2, pre ? P : nullptr);
    if (pre) {
        ctc_fb_kernel<true><<<Nn * 2, 64, 0, stream>>>(P, targets, tlen, ilen, d2, wsA, wsB);
    } else {
        ctc_fb_kernel<false><<<Nn * 2, 64, 0, stream>>>(logits, targets, tlen, ilen, d2, wsA, wsB);
    }
    ctc_combine_kernel<<<Nn, 64, 0, stream>>>(wsA, wsB, targets, tlen, out);
}

// Round 7
// 166.077 us; speedup vs baseline: 3.2041x; 1.4085x over previous
//
#include <hip/hip_runtime.h>
#include <cstdint>
#include <cstddef>

#define NEGV (-1e30f)
#define IL2f 1.44269504088896340736f
#define LN2f 0.693147180559945309417f

__device__ __forceinline__ float exp2_hw(float x) { return __builtin_amdgcn_exp2f(x); }
__device__ __forceinline__ float log2_hw(float x) { return __builtin_amdgcn_logf(x); }

constexpr int Nn = 64, Cc = 64, Tt = 4000, Ss = 100;

// Full-wave lane shifts via DPP; bound_ctrl=true => shifted-in lanes read 0.
__device__ __forceinline__ float wave_shr1(float x) {  // lane n <- lane n-1
    return __int_as_float(__builtin_amdgcn_update_dpp(0, __float_as_int(x), 0x138, 0xF, 0xF, true));
}
__device__ __forceinline__ float wave_shl1(float x) {  // lane n <- lane n+1
    return __int_as_float(__builtin_amdgcn_update_dpp(0, __float_as_int(x), 0x130, 0xF, 0xF, true));
}
__device__ __forceinline__ int wave_shr1_i(int x) {
    return __builtin_amdgcn_update_dpp(0, x, 0x138, 0xF, 0xF, true);
}
__device__ __forceinline__ int wave_shl1_i(int x) {
    return __builtin_amdgcn_update_dpp(0, x, 0x130, 0xF, 0xF, true);
}

typedef float f4 __attribute__((ext_vector_type(4)));
#define LD4(p) (*(const f4*)(p))

// -------- Kernel 1: fused per-(n,t) log2-softmax denominator + probabilities --------
__global__ __launch_bounds__(256) void ctc_softmax_kernel(
    const float* __restrict__ logits, float* __restrict__ d2, float* __restrict__ P)
{
    const int t4 = (blockIdx.x * 256 + threadIdx.x) * 4;
    const int n = blockIdx.y;
    if (t4 >= Tt) return;
    const float* __restrict__ p = logits + (size_t)n * Cc * Tt + t4;
    f4 m, s;
    {
        f4 v = LD4(p);
        #pragma unroll
        for (int i = 0; i < 4; ++i) { m[i] = v[i] * IL2f; s[i] = 1.f; }
    }
    #pragma unroll 4
    for (int c = 1; c < Cc; ++c) {
        f4 v = LD4(p + (size_t)c * Tt);
        #pragma unroll
        for (int i = 0; i < 4; ++i) {
            float vi = v[i] * IL2f;
            float nm = fmaxf(m[i], vi);
            s[i] = s[i] * exp2_hw(m[i] - nm) + exp2_hw(vi - nm);
            m[i] = nm;
        }
    }
    f4 d;
    #pragma unroll
    for (int i = 0; i < 4; ++i) d[i] = m[i] + log2_hw(s[i]);
    *(f4*)(d2 + (size_t)n * Tt + t4) = d;
    if (P) {
        float* __restrict__ dst = P + (size_t)n * Cc * Tt + t4;
        #pragma unroll 4
        for (int c = 0; c < Cc; ++c) {
            f4 v = LD4(p + (size_t)c * Tt);
            f4 o;
            #pragma unroll
            for (int i = 0; i < 4; ++i) o[i] = exp2_hw(fmaf(v[i], IL2f, -d[i]));
            *(f4*)(dst + (size_t)c * Tt) = o;
        }
    }
}

// ---------------- Kernel 2: fwd/bwd recurrence, linear domain, per-lane exponent ----
// 16-step groups, 3-slot register ring, lead-2 prefetch (~1000 cy) to cover HBM
// latency. Renorm + cross-lane E reconcile every 8 steps (windows). Slots/indices
// are all compile-time (rule: runtime-indexed arrays spill to scratch).
template<bool PRE>
__global__ __launch_bounds__(64) void ctc_fb_kernel(
    const float* __restrict__ PR, const int* __restrict__ targets,
    const int* __restrict__ tlen, const int* __restrict__ ilen,
    const float* __restrict__ d2, float* __restrict__ wsA, float* __restrict__ wsB)
{
    const int bid = blockIdx.x;
    const int n = bid >> 1;
    const bool bwd = bid & 1;
    const int lane = threadIdx.x;
    const int tl = tlen[n];
    const int Tn = ilen[n];
    const int L = 2 * tl + 1;
    const int mid = Tn >> 1;
    const int s0 = 4 * lane;

    const int j1 = min(2 * lane, Ss - 1);
    const int j3 = min(2 * lane + 1, Ss - 1);
    const int base = n * Ss;
    const int tg1 = targets[base + j1];
    const int tg3 = targets[base + j3];
    const int tg1m = targets[base + max(2 * lane - 1, 0)];
    const int tg3p = targets[base + min(2 * lane + 2, Ss - 1)];

    const float sk1f = ((s0 + 1 >= 3) && (tg1 != tg1m)) ? 1.f : 0.f;
    const float sk3f = (tg3 != tg1) ? 1.f : 0.f;
    const float sk1b = ((s0 + 3 < L) && (tg3 != tg1)) ? 1.f : 0.f;
    const float sk3b = ((s0 + 5 < L) && (tg3p != tg3)) ? 1.f : 0.f;

    const float* __restrict__ rB = PR + (size_t)(n * Cc) * Tt;
    const float* __restrict__ r1 = PR + (size_t)(n * Cc + tg1) * Tt;
    const float* __restrict__ r3 = PR + (size_t)(n * Cc + tg3) * Tt;
    const float* __restrict__ rD = d2 + (size_t)n * Tt;

    float a0, a1, a2, a3;
    int E = 0;

    if (!bwd) {
        float pB0, p10;
        if constexpr (PRE) { pB0 = rB[0]; p10 = r1[0]; }
        else {
            const float dv = rD[0];
            pB0 = exp2_hw(fmaf(rB[0], IL2f, -dv));
            p10 = exp2_hw(fmaf(r1[0], IL2f, -dv));
        }
        a0 = (lane == 0) ? pB0 : 0.f;
        a1 = (lane == 0) ? p10 : 0.f;
        a2 = 0.f; a3 = 0.f;
    } else {
        const int te = Tn - 1;
        float pBe, p1e, p3e;
        if constexpr (PRE) { pBe = rB[te]; p1e = r1[te]; p3e = r3[te]; }
        else {
            const float dv = rD[te];
            pBe = exp2_hw(fmaf(rB[te], IL2f, -dv));
            p1e = exp2_hw(fmaf(r1[te], IL2f, -dv));
            p3e = exp2_hw(fmaf(r3[te], IL2f, -dv));
        }
        const int sl = 2 * tl;
        a0 = (s0 == sl) ? pBe : 0.f;
        a1 = (s0 + 1 == sl - 1) ? p1e : 0.f;
        a2 = (s0 + 2 == sl) ? pBe : 0.f;
        a3 = (s0 + 3 == sl - 1) ? p3e : 0.f;
    }

    f4 bB[3][4], bU[3][4], bW[3][4], bD[3][4];

    #define GETP(arr, sl, k) (arr[sl][(k) >> 2][(k) & 3])

    if (!bwd) {
        const int tB = mid;                      // steps t = 1..tB
        const int gHi = tB >> 4;                 // 16-step groups

        #define ISSUE_F(gg, sl) {                                                   \
            const int gc_ = min((gg), gHi); const int bo_ = gc_ * 16;               \
            bB[sl][0]=LD4(rB+bo_); bB[sl][1]=LD4(rB+bo_+4);                         \
            bB[sl][2]=LD4(rB+bo_+8); bB[sl][3]=LD4(rB+bo_+12);                      \
            bU[sl][0]=LD4(r1+bo_); bU[sl][1]=LD4(r1+bo_+4);                         \
            bU[sl][2]=LD4(r1+bo_+8); bU[sl][3]=LD4(r1+bo_+12);                      \
            bW[sl][0]=LD4(r3+bo_); bW[sl][1]=LD4(r3+bo_+4);                         \
            bW[sl][2]=LD4(r3+bo_+8); bW[sl][3]=LD4(r3+bo_+12);                      \
            if constexpr (!PRE) {                                                   \
                bD[sl][0]=LD4(rD+bo_); bD[sl][1]=LD4(rD+bo_+4);                     \
                bD[sl][2]=LD4(rD+bo_+8); bD[sl][3]=LD4(rD+bo_+12); }               \
        }

        #define BODY_F(gg, us, is) {                                                \
            ISSUE_F((gg) + 2, is);                                                  \
            _Pragma("unroll")                                                       \
            for (int w = 0; w < 2; ++w) {                                           \
                const int Eu = wave_shr1_i(E);                                      \
                const int eb = min(max(127 + (Eu - E), 0), 230);                    \
                const float sc = __int_as_float((unsigned)eb << 23);                \
                const float sk1fs = sk1f * sc;                                      \
                _Pragma("unroll")                                                   \
                for (int kk = 0; kk < 8; ++kk) {                                    \
                    const int k = w * 8 + kk;                                       \
                    const int t = (gg) * 16 + k;                                    \
                    if (t >= 1 && t <= tB) {                                        \
                        float pB, p1, p3;                                           \
                        if constexpr (PRE) {                                        \
                            pB = GETP(bB, us, k); p1 = GETP(bU, us, k);             \
                            p3 = GETP(bW, us, k);                                   \
                        } else {                                                    \
                            const float dv = GETP(bD, us, k);                       \
                            pB = exp2_hw(fmaf(GETP(bB, us, k), IL2f, -dv));         \
                            p1 = exp2_hw(fmaf(GETP(bU, us, k), IL2f, -dv));         \
                            p3 = exp2_hw(fmaf(GETP(bW, us, k), IL2f, -dv));         \
                        }                                                           \
                        const float u3 = wave_shr1(a3);                             \
                        const float n3 = fmaf(a1, sk3f, a3 + a2) * p3;              \
                        const float n2 = (a2 + a1) * pB;                            \
                        const float n1 = fmaf(u3, sk1fs, a1 + a0) * p1;             \
                        const float n0 = fmaf(u3, sc, a0) * pB;                     \
                        a0 = n0; a1 = n1; a2 = n2; a3 = n3;                         \
                    }                                                               \
                }                                                                   \
                const float mx = fmaxf(fmaxf(a0, a1), fmaxf(a2, a3));               \
                const int me = (int)(__float_as_uint(mx) >> 23);                    \
                const float sc2 = __int_as_float((unsigned)(254 - me) << 23);       \
                a0 *= sc2; a1 *= sc2; a2 *= sc2; a3 *= sc2;                         \
                E = (mx > 0.f) ? (E + me - 127) : Eu;                               \
            }                                                                       \
        }

        ISSUE_F(0, 0);
        ISSUE_F(1, 1);
        for (int g = 0; g <= gHi; g += 3) {
            BODY_F(g, 0, 2);
            if (g + 1 <= gHi) BODY_F(g + 1, 1, 0);
            if (g + 2 <= gHi) BODY_F(g + 2, 2, 1);
        }
        #undef BODY_F
        #undef ISSUE_F
    } else {
        const int tB = Tn - 2, tA = mid + 1;     // steps t = tB .. tA (descending)
        const int gHi = tB >> 4, gLo = tA >> 4;

        #define ISSUE_B(gg, sl) {                                                   \
            const int gc_ = max((gg), 0); const int bo_ = gc_ * 16;                 \
            bB[sl][0]=LD4(rB+bo_); bB[sl][1]=LD4(rB+bo_+4);                         \
            bB[sl][2]=LD4(rB+bo_+8); bB[sl][3]=LD4(rB+bo_+12);                      \
            bU[sl][0]=LD4(r1+bo_); bU[sl][1]=LD4(r1+bo_+4);                         \
            bU[sl][2]=LD4(r1+bo_+8); bU[sl][3]=LD4(r1+bo_+12);                      \
            bW[sl][0]=LD4(r3+bo_); bW[sl][1]=LD4(r3+bo_+4);                         \
            bW[sl][2]=LD4(r3+bo_+8); bW[sl][3]=LD4(r3+bo_+12);                      \
            if constexpr (!PRE) {                                                   \
                bD[sl][0]=LD4(rD+bo_); bD[sl][1]=LD4(rD+bo_+4);                     \
                bD[sl][2]=LD4(rD+bo_+8); bD[sl][3]=LD4(rD+bo_+12); }               \
        }

        #define BODY_B(gg, us, is) {                                                \
            ISSUE_B((gg) - 2, is);                                                  \
            _Pragma("unroll")                                                       \
            for (int w = 1; w >= 0; --w) {                                          \
                const int Ed = wave_shl1_i(E);                                      \
                const int eb = min(max(127 + (Ed - E), 0), 230);                    \
                const float sc = __int_as_float((unsigned)eb << 23);                \
                const float sk3bs = sk3b * sc;                                      \
                _Pragma("unroll")                                                   \
                for (int kk = 7; kk >= 0; --kk) {                                   \
                    const int k = w * 8 + kk;                                       \
                    const int t = (gg) * 16 + k;                                    \
                    if (t >= tA && t <= tB) {                                       \
                        float pB, p1, p3;                                           \
                        if constexpr (PRE) {                                        \
                            pB = GETP(bB, us, k); p1 = GETP(bU, us, k);             \
                            p3 = GETP(bW, us, k);                                   \
                        } else {                                                    \
                            const float dv = GETP(bD, us, k);                       \
                            pB = exp2_hw(fmaf(GETP(bB, us, k), IL2f, -dv));         \
                            p1 = exp2_hw(fmaf(GETP(bU, us, k), IL2f, -dv));         \
                            p3 = exp2_hw(fmaf(GETP(bW, us, k), IL2f, -dv));         \
                        }                                                           \
                        const float d0 = wave_shl1(a0);                             \
                        const float d1 = wave_shl1(a1);                             \
                        const float n0 = (a0 + a1) * pB;                            \
                        const float n1 = fmaf(a3, sk1b, a1 + a2) * p1;              \
                        const float n2 = (a2 + a3) * pB;                            \
                        const float n3 = fmaf(d1, sk3bs, fmaf(d0, sc, a3)) * p3;    \
                        a0 = n0; a1 = n1; a2 = n2; a3 = n3;                         \
                    }                                                               \
                }                                                                   \
                const float mx = fmaxf(fmaxf(a0, a1), fmaxf(a2, a3));               \
                const int me = (int)(__float_as_uint(mx) >> 23);                    \
                const float sc2 = __int_as_float((unsigned)(254 - me) << 23);       \
                a0 *= sc2; a1 *= sc2; a2 *= sc2; a3 *= sc2;                         \
                E = (mx > 0.f) ? (E + me - 127) : Ed;                               \
            }                                                                       \
        }

        ISSUE_B(gHi, 0);
        ISSUE_B(gHi - 1, 1);
        for (int g = gHi; g >= gLo; g -= 3) {
            BODY_B(g, 0, 2);
            if (g - 1 >= gLo) BODY_B(g - 1, 1, 0);
            if (g - 2 >= gLo) BODY_B(g - 2, 2, 1);
        }
        #undef BODY_B
        #undef ISSUE_B
    }
    #undef GETP

    // convert to log2 domain for the combine kernel
    float* dst = (bwd ? wsB : wsA) + n * 256;
    const float Ef = (float)E;
    f4 o;
    o[0] = (s0     < L && a0 > 0.f) ? log2_hw(a0) + Ef : NEGV;
    o[1] = (s0 + 1 < L && a1 > 0.f) ? log2_hw(a1) + Ef : NEGV;
    o[2] = (s0 + 2 < L && a2 > 0.f) ? log2_hw(a2) + Ef : NEGV;
    o[3] = (s0 + 3 < L && a3 > 0.f) ? log2_hw(a3) + Ef : NEGV;
    *(f4*)(dst + s0) = o;
}

// ---------------- Kernel 3: splice alpha*beta, lse over states, mean ----------------
__global__ __launch_bounds__(64) void ctc_combine_kernel(
    const float* __restrict__ wsA, const float* __restrict__ wsB,
    const int* __restrict__ targets, const int* __restrict__ tlen,
    float* __restrict__ out)
{
    const int n = blockIdx.x;
    const int lane = threadIdx.x;
    const int tl = tlen[n];
    const int L = 2 * tl + 1;
    float vals[4];
    float vmax = NEGV;
    #pragma unroll
    for (int k = 0; k < 4; ++k) {
        const int s = lane + (k << 6);
        float v = NEGV;
        if (s < L) {
            const float al = wsA[n * 256 + s];
            const float b0 = wsB[n * 256 + s];
            const float b1 = (s + 1 < L) ? wsB[n * 256 + s + 1] : NEGV;
            const bool skip = (s & 1) && (s + 2 < L) &&
                (targets[n * Ss + (s >> 1) + 1] != targets[n * Ss + (s >> 1)]);
            const float b2 = skip ? wsB[n * 256 + s + 2] : NEGV;
            const float m3 = fmaxf(fmaxf(b0, b1), b2);
            const float B = m3 + log2_hw(exp2_hw(b0 - m3) + exp2_hw(b1 - m3) + exp2_hw(b2 - m3));
            v = al + B;
        }
        vals[k] = v;
        vmax = fmaxf(vmax, v);
    }
    #pragma unroll
    for (int o = 32; o; o >>= 1) vmax = fmaxf(vmax, __shfl_xor(vmax, o));
    float ssum = 0.f;
    #pragma unroll
    for (int k = 0; k < 4; ++k) ssum += exp2_hw(vals[k] - vmax);
    #pragma unroll
    for (int o = 32; o; o >>= 1) ssum += __shfl_xor(ssum, o);
    if (lane == 0) {
        const float total2 = vmax + log2_hw(ssum);
        const float loss = -LN2f * total2;
        atomicAdd(out, loss / ((float)tl * (float)Nn));
    }
}

extern "C" void kernel_launch(void* const* d_in, const int* in_sizes, int n_in,
                              void* d_out, int out_size, void* d_ws, size_t ws_size,
                              hipStream_t stream) {
    const float* logits = (const float*)d_in[0];
    const int* targets  = (const int*)d_in[1];
    const int* tlen     = (const int*)d_in[2];
    const int* ilen     = (const int*)d_in[3];
    float* out = (float*)d_out;

    float* wsA = (float*)d_ws;                     // 64*256
    float* wsB = wsA + Nn * 256;                   // 64*256
    float* d2  = wsB + Nn * 256;                   // 64*4000
    float* P   = d2 + (size_t)Nn * Tt;             // 64*64*4000 (if it fits)
    const size_t need = ((size_t)Nn * 256 * 2 + (size_t)Nn * Tt
                         + (size_t)Nn * Cc * Tt) * sizeof(float);
    const bool pre = (ws_size >= need);

    hipMemsetAsync(d_out, 0, sizeof(float), stream);
    ctc_softmax_kernel<<<dim3(4, Nn), 256, 0, stream>>>(logits, d2, pre ? P : nullptr);
    if (pre) {
        ctc_fb_kernel<true><<<Nn * 2, 64, 0, stream>>>(P, targets, tlen, ilen, d2, wsA, wsB);
    } else {
        ctc_fb_kernel<false><<<Nn * 2, 64, 0, stream>>>(logits, targets, tlen, ilen, d2, wsA, wsB);
    }
    ctc_combine_kernel<<<Nn, 64, 0, stream>>>(wsA, wsB, targets, tlen, out);
}